// Round 10
// baseline (186.177 us; speedup 1.0000x reference)
//
#include <hip/hip_runtime.h>
#include <cstdint>
#include <cstddef>

#define G 256
#define EPER 4096
#define F 128

typedef __attribute__((ext_vector_type(8))) short short8;
typedef __attribute__((ext_vector_type(4))) float f32x4;

__device__ inline unsigned short f2bf(float f) {
    unsigned u = __float_as_uint(f);
    u += 0x7FFFu + ((u >> 16) & 1u);
    return (unsigned short)(u >> 16);
}
__device__ inline float bf2f(unsigned short b) { return __uint_as_float(((unsigned)b) << 16); }

// -------------------- W pre-split: [Wr;Wl] -> fragment-major bf16 hi/lo --------------------
// Wf layout per stage (shorts): hi[32][128][8] at s*65536, lo at s*65536+32768.
__global__ __launch_bounds__(256) void k_wsplit(const float* __restrict__ Wr1, const float* __restrict__ Wl1,
                                                const float* __restrict__ Wr2, const float* __restrict__ Wl2,
                                                const float* __restrict__ Wr3, const float* __restrict__ Wl3,
                                                unsigned short* __restrict__ Wf) {
    int gid = blockIdx.x * 256 + threadIdx.x;   // 0..98303
    int s = gid >> 15;
    int idx = gid & 32767;
    int j = idx & 7, col = (idx >> 3) & 127, ko = idx >> 10;
    int k = ko * 8 + j;
    const float* Wr = (s == 0) ? Wr1 : (s == 1) ? Wr2 : Wr3;
    const float* Wl = (s == 0) ? Wl1 : (s == 1) ? Wl2 : Wl3;
    float f = (k < 128) ? Wr[(size_t)k * 128 + col] : Wl[(size_t)(k - 128) * 128 + col];
    unsigned short h1 = f2bf(f), h2 = f2bf(f - bf2f(h1));
    Wf[(size_t)s * 65536 + idx] = h1;
    Wf[(size_t)s * 65536 + 32768 + idx] = h2;
}

// -------------------- aggregation: agg = Adj @ x on MFMA (writes AGG buffer) ---------------
template<int NS, int BM, bool USE_MAP>
__global__ __launch_bounds__(256) void k_agg(const float* __restrict__ X,
                                             const int* __restrict__ src,
                                             const int* __restrict__ dst,
                                             const int* __restrict__ cmap,
                                             const float* __restrict__ Ain,
                                             float* __restrict__ Aout) {
    constexpr bool SPLIT = (NS > BM);
    constexpr int RW = BM / 4;
    constexpr int MT = RW / 16;
    constexpr int NS4 = NS / 4;
    __shared__ unsigned adjc[BM * NS4];
    __shared__ short adjT[4 * BM * 8];
    __shared__ short xs[3][4 * 128 * 8];
    __shared__ int smap[256];

    const int b = blockIdx.x, t = threadIdx.x;
    const int g = SPLIT ? (b >> 1) : b;
    const int mbase = SPLIT ? (b & 1) * BM : 0;

    {
        uint4* z = (uint4*)adjc;
        #pragma unroll
        for (int i = t; i < BM * NS4 / 4; i += 256) z[i] = uint4{0, 0, 0, 0};
    }
    if (USE_MAP) smap[t] = cmap[g * 256 + t];
    __syncthreads();

    const int* sg = src + (size_t)g * EPER;
    const int* dg = dst + (size_t)g * EPER;
    #pragma unroll 4
    for (int j = 0; j < 16; ++j) {
        int e = j * 256 + t;
        int s = sg[e], d = dg[e];
        if (USE_MAP) { s = smap[s]; d = smap[d]; }
        int m = d - mbase;
        if (s >= 0 && (unsigned)m < (unsigned)BM) {
            int pos = (s + 4 * m) & (NS - 1);
            __hip_atomic_fetch_add(&adjc[m * NS4 + (pos >> 2)], 1u << ((pos & 3) * 8),
                                   __ATOMIC_RELAXED, __HIP_MEMORY_SCOPE_WORKGROUP);
        }
    }

    const float* xsrc = USE_MAP ? (Ain + (size_t)g * 32768 + 16384) : (X + (size_t)g * 32768);

    f32x4 acc[MT][8];
    #pragma unroll
    for (int i = 0; i < MT; ++i)
        #pragma unroll
        for (int c = 0; c < 8; ++c) acc[i][c] = f32x4{0.f, 0.f, 0.f, 0.f};

    const int lane = t & 63, wv = t >> 6;
    constexpr int TPR = 256 / BM;
    constexpr int CPT = 32 / TPR;
    const int mA = t / TPR, kgA = (t % TPR) * CPT;
    const int nX = t & 127, kgX = (t >> 7) * 16;

    for (int k0 = 0; k0 < NS; k0 += 32) {
        __syncthreads();
        {
            unsigned short cs[CPT];
            #pragma unroll
            for (int q = 0; q < CPT / 4; ++q) {
                unsigned w = adjc[mA * NS4 + ((((k0 + kgA) >> 2) + mA + q) & (NS4 - 1))];
                cs[q * 4 + 0] = f2bf((float)(w & 255u));
                cs[q * 4 + 1] = f2bf((float)((w >> 8) & 255u));
                cs[q * 4 + 2] = f2bf((float)((w >> 16) & 255u));
                cs[q * 4 + 3] = f2bf((float)(w >> 24));
            }
            #pragma unroll
            for (int c = 0; c < CPT / 8; ++c) {
                short8 w8;
                #pragma unroll
                for (int j = 0; j < 8; ++j) w8[j] = (short)cs[c * 8 + j];
                *(short8*)&adjT[((kgA >> 3) + c) * BM * 8 + mA * 8] = w8;
            }
        }
        {
            float v[16];
            #pragma unroll
            for (int i = 0; i < 16; ++i)
                v[i] = xsrc[(size_t)(k0 + kgX + i) * F + nX];
            #pragma unroll
            for (int c = 0; c < 2; ++c) {
                short8 h1, h2, h3;
                #pragma unroll
                for (int j = 0; j < 8; ++j) {
                    float f = v[c * 8 + j];
                    unsigned short a1 = f2bf(f);
                    float r = f - bf2f(a1);
                    unsigned short a2 = f2bf(r);
                    float r2 = r - bf2f(a2);
                    h1[j] = (short)a1; h2[j] = (short)a2; h3[j] = (short)f2bf(r2);
                }
                int ko = (kgX >> 3) + c;
                *(short8*)&xs[0][ko * 1024 + nX * 8] = h1;
                *(short8*)&xs[1][ko * 1024 + nX * 8] = h2;
                *(short8*)&xs[2][ko * 1024 + nX * 8] = h3;
            }
        }
        __syncthreads();
        short8 afr[MT];
        #pragma unroll
        for (int mt = 0; mt < MT; ++mt)
            afr[mt] = *(const short8*)&adjT[(lane >> 4) * BM * 8 + (wv * RW + mt * 16 + (lane & 15)) * 8];
        #pragma unroll
        for (int s = 0; s < 3; ++s) {
            #pragma unroll
            for (int ct = 0; ct < 8; ++ct) {
                short8 bfr = *(const short8*)&xs[s][(lane >> 4) * 1024 + (ct * 16 + (lane & 15)) * 8];
                #pragma unroll
                for (int mt = 0; mt < MT; ++mt)
                    acc[mt][ct] = __builtin_amdgcn_mfma_f32_16x16x32_bf16(afr[mt], bfr, acc[mt][ct], 0, 0, 0);
            }
        }
    }

    float* Ag = Aout + (size_t)g * 32768;
    #pragma unroll
    for (int mt = 0; mt < MT; ++mt) {
        int r0 = mbase + wv * RW + mt * 16 + (lane >> 4) * 4;
        #pragma unroll
        for (int ct = 0; ct < 8; ++ct) {
            int col = ct * 16 + (lane & 15);
            #pragma unroll
            for (int r = 0; r < 4; ++r)
                Ag[(size_t)(r0 + r) * F + col] = acc[mt][ct][r];
        }
    }
}

// -------------------- conv GEMM on MFMA, LDS-free / barrier-free --------------------
// h = relu([X | AGG] @ [Wr;Wl] + b). Per-lane A rows read global->reg (32B contiguous),
// split to bf16 hi/lo in-register; W fragments stream from pre-split Wf (L2-resident).
// 3 MFMA passes (a1w1 + a2w1 + a1w2). No LDS -> occupancy VGPR-bound, TLP hides latency.
template<int NS, bool FIRST>
__global__ __launch_bounds__(512) void k_gemm(const float* __restrict__ X,
                                              float* __restrict__ A,
                                              const float* __restrict__ AGG,
                                              const unsigned short* __restrict__ Whi,
                                              const float* __restrict__ bias) {
    constexpr int L2NS = (NS == 256) ? 8 : (NS == 128) ? 7 : 6;
    const int t = threadIdx.x;
    const int m0 = blockIdx.x * 128;
    const int lane = t & 63;
    const int wv = t >> 6, wr = wv >> 1, wc = wv & 1;   // 4 row-bands x 2 col-halves
    const int l15 = lane & 15, lko = lane >> 4;
    const unsigned short* Wlo = Whi + 32768;

    f32x4 acc[2][4];
    #pragma unroll
    for (int i = 0; i < 2; ++i)
        #pragma unroll
        for (int c = 0; c < 4; ++c) acc[i][c] = f32x4{0.f, 0.f, 0.f, 0.f};

    const float* px[2];
    const float* pa[2];
    #pragma unroll
    for (int mt = 0; mt < 2; ++mt) {
        int m = m0 + wr * 32 + mt * 16 + l15;
        int gg = m >> L2NS, nn = m & (NS - 1);
        px[mt] = FIRST ? (X + (size_t)m * F)
                       : (A + (size_t)gg * 32768 + (size_t)(128 + nn) * F);
        pa[mt] = AGG + (size_t)gg * 32768 + (size_t)nn * F;
    }

    #pragma unroll 2
    for (int kt = 0; kt < 8; ++kt) {
        short8 a1f[2], a2f[2];
        #pragma unroll
        for (int mt = 0; mt < 2; ++mt) {
            const float* p = ((kt < 4) ? (px[mt] + kt * 32) : (pa[mt] + (kt - 4) * 32)) + lko * 8;
            float4 fa = *(const float4*)p;
            float4 fb = *(const float4*)(p + 4);
            float vv[8] = {fa.x, fa.y, fa.z, fa.w, fb.x, fb.y, fb.z, fb.w};
            #pragma unroll
            for (int j = 0; j < 8; ++j) {
                unsigned short h1 = f2bf(vv[j]);
                unsigned short h2 = f2bf(vv[j] - bf2f(h1));
                a1f[mt][j] = (short)h1; a2f[mt][j] = (short)h2;
            }
        }
        const int kog = kt * 4 + lko;
        #pragma unroll
        for (int ct = 0; ct < 4; ++ct) {
            int col = wc * 64 + ct * 16 + l15;
            size_t off = ((size_t)kog * 128 + col) * 8;
            short8 w1 = *(const short8*)(Whi + off);
            short8 w2 = *(const short8*)(Wlo + off);
            #pragma unroll
            for (int mt = 0; mt < 2; ++mt) {
                acc[mt][ct] = __builtin_amdgcn_mfma_f32_16x16x32_bf16(a1f[mt], w1, acc[mt][ct], 0, 0, 0);
                acc[mt][ct] = __builtin_amdgcn_mfma_f32_16x16x32_bf16(a2f[mt], w1, acc[mt][ct], 0, 0, 0);
                acc[mt][ct] = __builtin_amdgcn_mfma_f32_16x16x32_bf16(a1f[mt], w2, acc[mt][ct], 0, 0, 0);
            }
        }
    }

    // epilogue: D col=lane&15 (per ct), row=(lane>>4)*4+reg
    #pragma unroll
    for (int ct = 0; ct < 4; ++ct) {
        int col = wc * 64 + ct * 16 + l15;
        float bv = bias[col];
        #pragma unroll
        for (int mt = 0; mt < 2; ++mt) {
            int r0 = m0 + wr * 32 + mt * 16 + lko * 4;
            #pragma unroll
            for (int r = 0; r < 4; ++r) {
                int m = r0 + r;
                int gg = m >> L2NS, nn = m & (NS - 1);
                A[(size_t)gg * 32768 + (size_t)nn * F + col] = fmaxf(acc[mt][ct][r] + bv, 0.f);
            }
        }
    }
}

// -------------------- top-k pool + readout + cmap update (1024 threads) --------------------
template<int N, int K, int STAGE>
__global__ __launch_bounds__(1024) void k_pool(float* __restrict__ A,
                                               float* __restrict__ R,
                                               int* __restrict__ cmap,
                                               const float* __restrict__ wp) {
    __shared__ float sc[N];
    __shared__ unsigned long long keys[N];
    __shared__ float hp[K * F];
    __shared__ int sel[K];
    __shared__ int inv[N];
    __shared__ float wn[F];
    __shared__ float gates[K];
    __shared__ float pmx[8 * F];
    __shared__ float psm[8 * F];
    __shared__ float snorm_s;
    const int g = blockIdx.x, t = threadIdx.x;
    const float* h = A + (size_t)g * 32768;
    const int lane = t & 63, wv16 = t >> 6;

    if (t < 64) {
        float v = wp[t] * wp[t] + wp[t + 64] * wp[t + 64];
        #pragma unroll
        for (int o = 32; o; o >>= 1) v += __shfl_xor(v, o);
        if (t == 0) snorm_s = sqrtf(v);
    }
    __syncthreads();
    if (t < 128) wn[t] = wp[t] / snorm_s;
    __syncthreads();

    {
        const int r16 = lane >> 4, l16 = lane & 15;
        float4 w0 = *(const float4*)&wn[l16 * 8];
        float4 w1 = *(const float4*)&wn[l16 * 8 + 4];
        #pragma unroll
        for (int n0 = 0; n0 < N; n0 += 64) {
            int r = n0 + wv16 * 4 + r16;
            const float* hr = h + (size_t)r * F + l16 * 8;
            float4 v0 = *(const float4*)hr;
            float4 v1 = *(const float4*)(hr + 4);
            float p = v0.x * w0.x + v0.y * w0.y + v0.z * w0.z + v0.w * w0.w
                    + v1.x * w1.x + v1.y * w1.y + v1.z * w1.z + v1.w * w1.w;
            p += __shfl_xor(p, 1); p += __shfl_xor(p, 2);
            p += __shfl_xor(p, 4); p += __shfl_xor(p, 8);
            if (l16 == 0) sc[r] = p;
        }
    }
    __syncthreads();

    if (t < N) {
        unsigned u = __float_as_uint(sc[t]);
        u = (u & 0x80000000u) ? ~u : (u | 0x80000000u);
        keys[t] = ((unsigned long long)u << 32) | (unsigned)(~t);
    }
    __syncthreads();
    for (int kk = 2; kk <= N; kk <<= 1) {
        for (int j = kk >> 1; j > 0; j >>= 1) {
            if (t < N) {
                int ixj = t ^ j;
                if (ixj > t) {
                    unsigned long long a = keys[t], b = keys[ixj];
                    bool up = (t & kk) == 0;
                    if (up ? (a < b) : (a > b)) { keys[t] = b; keys[ixj] = a; }
                }
            }
            __syncthreads();
        }
    }

    if (t < K) sel[t] = (int)(~(unsigned)keys[t]);
    if (t < N) inv[t] = -1;
    __syncthreads();
    if (t < K) {
        inv[sel[t]] = t;
        gates[t] = tanhf(sc[sel[t]]);
    }
    __syncthreads();
    if (t < 256) {
        int c = (STAGE == 1) ? t : cmap[g * 256 + t];
        cmap[g * 256 + t] = (c >= 0) ? inv[c] : -1;
    }

    {
        const int f = t & 127, seg = t >> 7;
        float mx = -INFINITY, sm = 0.f;
        for (int j = seg; j < K; j += 8) {
            float v = h[(size_t)sel[j] * F + f] * gates[j];
            hp[j * F + f] = v;
            mx = fmaxf(mx, v);
            sm += v;
        }
        pmx[seg * F + f] = mx;
        psm[seg * F + f] = sm;
    }
    __syncthreads();

    if (t < 128) {
        float m = -INFINITY, s = 0.f;
        #pragma unroll
        for (int q = 0; q < 8; ++q) {
            m = fmaxf(m, pmx[q * F + t]);
            s += psm[q * F + t];
        }
        R[(size_t)g * 768 + (STAGE - 1) * 256 + t] = m;
        R[(size_t)g * 768 + (STAGE - 1) * 256 + 128 + t] = s * (1.0f / K);
    }

    if (STAGE < 3) {
        float4* dst = (float4*)(A + (size_t)g * 32768 + 128 * F);
        const float4* srcp = (const float4*)hp;
        for (int i = t; i < K * F / 4; i += 1024) dst[i] = srcp[i];
    }
}

// -------------------- final MLP + log_softmax (split-K, 1024 threads) --------------------
__global__ __launch_bounds__(1024) void k_mlp(const float* __restrict__ R,
                                              const float* __restrict__ W1, const float* __restrict__ b1,
                                              const float* __restrict__ W2, const float* __restrict__ b2,
                                              const float* __restrict__ W3, const float* __restrict__ b3,
                                              float* __restrict__ out) {
    __shared__ float z[768];
    __shared__ float part[8][128];
    __shared__ float z2[128];
    __shared__ float z3[64];
    __shared__ float lg[10];
    __shared__ float lse;
    const int g = blockIdx.x, t = threadIdx.x;

    if (t < 768) z[t] = R[(size_t)g * 768 + t];
    __syncthreads();

    {
        const int f = t & 127, seg = t >> 7;
        float acc = 0.f;
        const float* w = W1 + (size_t)(seg * 96) * 128 + f;
        const float* zz = z + seg * 96;
        #pragma unroll 8
        for (int k = 0; k < 96; ++k) acc = fmaf(zz[k], w[(size_t)k * 128], acc);
        part[seg][f] = acc;
    }
    __syncthreads();
    if (t < 128) {
        float a = b1[t];
        #pragma unroll
        for (int q = 0; q < 8; ++q) a += part[q][t];
        z2[t] = fmaxf(a, 0.f);
    }
    __syncthreads();

    if (t < 512) {
        const int f = t & 63, seg = t >> 6;
        float acc = 0.f;
        const float* w = W2 + (size_t)(seg * 16) * 64 + f;
        const float* zz = z2 + seg * 16;
        #pragma unroll
        for (int k = 0; k < 16; ++k) acc = fmaf(zz[k], w[(size_t)k * 64], acc);
        part[seg][f] = acc;
    }
    __syncthreads();
    if (t < 64) {
        float a = b2[t];
        #pragma unroll
        for (int q = 0; q < 8; ++q) a += part[q][t];
        z3[t] = fmaxf(a, 0.f);
    }
    __syncthreads();

    if (t < 10) {
        float a3 = b3[t];
        #pragma unroll 8
        for (int k = 0; k < 64; ++k) a3 = fmaf(z3[k], W3[(size_t)k * 10 + t], a3);
        lg[t] = a3;
    }
    __syncthreads();

    if (t == 0) {
        float m = lg[0];
        for (int c = 1; c < 10; ++c) m = fmaxf(m, lg[c]);
        float s = 0.f;
        for (int c = 0; c < 10; ++c) s += expf(lg[c] - m);
        lse = m + logf(s);
    }
    __syncthreads();
    if (t < 10) out[(size_t)g * 10 + t] = lg[t] - lse;
}

extern "C" void kernel_launch(void* const* d_in, const int* in_sizes, int n_in,
                              void* d_out, int out_size, void* d_ws, size_t ws_size,
                              hipStream_t stream) {
    (void)in_sizes; (void)n_in; (void)out_size; (void)ws_size;
    const float* x    = (const float*)d_in[0];
    const int*   src  = (const int*)d_in[1];
    const int*   dst  = (const int*)d_in[2];
    const float* Wr1  = (const float*)d_in[3];
    const float* Wrel1= (const float*)d_in[4];
    const float* b1   = (const float*)d_in[5];
    const float* wp1  = (const float*)d_in[6];
    const float* Wr2  = (const float*)d_in[7];
    const float* Wrel2= (const float*)d_in[8];
    const float* b2   = (const float*)d_in[9];
    const float* wp2  = (const float*)d_in[10];
    const float* Wr3  = (const float*)d_in[11];
    const float* Wrel3= (const float*)d_in[12];
    const float* b3   = (const float*)d_in[13];
    const float* wp3  = (const float*)d_in[14];
    const float* L1w  = (const float*)d_in[15];
    const float* L1b  = (const float*)d_in[16];
    const float* L2w  = (const float*)d_in[17];
    const float* L2b  = (const float*)d_in[18];
    const float* L3w  = (const float*)d_in[19];
    const float* L3b  = (const float*)d_in[20];

    float* A    = (float*)d_ws;                        // G*32768 f32  (h + pooled rows)
    int*   cmap = (int*)(A + (size_t)G * 32768);       // G*256 i32
    float* R    = (float*)(cmap + (size_t)G * 256);    // G*768 f32
    float* AGG  = R + (size_t)G * 768;                 // G*32768 f32  (agg output)
    unsigned short* Wf = (unsigned short*)(AGG + (size_t)G * 32768);  // 3*65536 shorts
    float* out  = (float*)d_out;

    // W pre-split (once per launch, all 3 stages)
    k_wsplit<<<384, 256, 0, stream>>>(Wr1, Wrel1, Wr2, Wrel2, Wr3, Wrel3, Wf);

    // stage 1
    k_agg<256, 128, false><<<G * 2, 256, 0, stream>>>(x, src, dst, nullptr, A, AGG);
    k_gemm<256, true><<<512, 512, 0, stream>>>(x, A, AGG, Wf, b1);
    k_pool<256, 128, 1><<<G, 1024, 0, stream>>>(A, R, cmap, wp1);
    // stage 2
    k_agg<128, 128, true><<<G, 256, 0, stream>>>(x, src, dst, cmap, A, AGG);
    k_gemm<128, false><<<256, 512, 0, stream>>>(nullptr, A, AGG, Wf + 65536, b2);
    k_pool<128, 64, 2><<<G, 1024, 0, stream>>>(A, R, cmap, wp2);
    // stage 3
    k_agg<64, 64, true><<<G, 256, 0, stream>>>(x, src, dst, cmap, A, AGG);
    k_gemm<64, false><<<128, 512, 0, stream>>>(nullptr, A, AGG, Wf + 131072, b3);
    k_pool<64, 32, 3><<<G, 1024, 0, stream>>>(A, R, cmap, wp3);
    // head
    k_mlp<<<G, 1024, 0, stream>>>(R, L1w, L1b, L2w, L2b, L3w, L3b, out);
}

// Round 11
// 158.791 us; speedup vs baseline: 1.1725x; 1.1725x over previous
//
#include <hip/hip_runtime.h>
#include <cstdint>
#include <cstddef>

#define G 256
#define EPER 4096
#define F 128

typedef __attribute__((ext_vector_type(8))) short short8;
typedef __attribute__((ext_vector_type(4))) float f32x4;

__device__ inline unsigned short f2bf(float f) {
    unsigned u = __float_as_uint(f);
    u += 0x7FFFu + ((u >> 16) & 1u);
    return (unsigned short)(u >> 16);
}
__device__ inline float bf2f(unsigned short b) { return __uint_as_float(((unsigned)b) << 16); }

// -------------------- W pre-split: [Wr;Wl] -> fragment-major bf16 hi/lo --------------------
// Per stage (shorts): hi[32 ko][128 col][8 j] at s*65536, lo at s*65536+32768.
__global__ __launch_bounds__(256) void k_wsplit(const float* __restrict__ Wr1, const float* __restrict__ Wl1,
                                                const float* __restrict__ Wr2, const float* __restrict__ Wl2,
                                                const float* __restrict__ Wr3, const float* __restrict__ Wl3,
                                                unsigned short* __restrict__ Wf) {
    int gid = blockIdx.x * 256 + threadIdx.x;   // 0..98303
    int s = gid >> 15;
    int idx = gid & 32767;
    int j = idx & 7, col = (idx >> 3) & 127, ko = idx >> 10;
    int k = ko * 8 + j;
    const float* Wr = (s == 0) ? Wr1 : (s == 1) ? Wr2 : Wr3;
    const float* Wl = (s == 0) ? Wl1 : (s == 1) ? Wl2 : Wl3;
    float f = (k < 128) ? Wr[(size_t)k * 128 + col] : Wl[(size_t)(k - 128) * 128 + col];
    unsigned short h1 = f2bf(f), h2 = f2bf(f - bf2f(h1));
    Wf[(size_t)s * 65536 + idx] = h1;
    Wf[(size_t)s * 65536 + 32768 + idx] = h2;
}

// -------------------- aggregation: agg = Adj @ x on MFMA (writes AGG buffer) ---------------
template<int NS, int BM, bool USE_MAP>
__global__ __launch_bounds__(256) void k_agg(const float* __restrict__ X,
                                             const int* __restrict__ src,
                                             const int* __restrict__ dst,
                                             const int* __restrict__ cmap,
                                             const float* __restrict__ Ain,
                                             float* __restrict__ Aout) {
    constexpr bool SPLIT = (NS > BM);
    constexpr int RW = BM / 4;
    constexpr int MT = RW / 16;
    constexpr int NS4 = NS / 4;
    __shared__ unsigned adjc[BM * NS4];
    __shared__ short adjT[4 * BM * 8];
    __shared__ short xs[3][4 * 128 * 8];
    __shared__ int smap[256];

    const int b = blockIdx.x, t = threadIdx.x;
    const int g = SPLIT ? (b >> 1) : b;
    const int mbase = SPLIT ? (b & 1) * BM : 0;

    {
        uint4* z = (uint4*)adjc;
        #pragma unroll
        for (int i = t; i < BM * NS4 / 4; i += 256) z[i] = uint4{0, 0, 0, 0};
    }
    if (USE_MAP) smap[t] = cmap[g * 256 + t];
    __syncthreads();

    const int* sg = src + (size_t)g * EPER;
    const int* dg = dst + (size_t)g * EPER;
    #pragma unroll 4
    for (int j = 0; j < 16; ++j) {
        int e = j * 256 + t;
        int s = sg[e], d = dg[e];
        if (USE_MAP) { s = smap[s]; d = smap[d]; }
        int m = d - mbase;
        if (s >= 0 && (unsigned)m < (unsigned)BM) {
            int pos = (s + 4 * m) & (NS - 1);
            __hip_atomic_fetch_add(&adjc[m * NS4 + (pos >> 2)], 1u << ((pos & 3) * 8),
                                   __ATOMIC_RELAXED, __HIP_MEMORY_SCOPE_WORKGROUP);
        }
    }

    const float* xsrc = USE_MAP ? (Ain + (size_t)g * 32768 + 16384) : (X + (size_t)g * 32768);

    f32x4 acc[MT][8];
    #pragma unroll
    for (int i = 0; i < MT; ++i)
        #pragma unroll
        for (int c = 0; c < 8; ++c) acc[i][c] = f32x4{0.f, 0.f, 0.f, 0.f};

    const int lane = t & 63, wv = t >> 6;
    constexpr int TPR = 256 / BM;
    constexpr int CPT = 32 / TPR;
    const int mA = t / TPR, kgA = (t % TPR) * CPT;
    const int nX = t & 127, kgX = (t >> 7) * 16;

    for (int k0 = 0; k0 < NS; k0 += 32) {
        __syncthreads();
        {
            unsigned short cs[CPT];
            #pragma unroll
            for (int q = 0; q < CPT / 4; ++q) {
                unsigned w = adjc[mA * NS4 + ((((k0 + kgA) >> 2) + mA + q) & (NS4 - 1))];
                cs[q * 4 + 0] = f2bf((float)(w & 255u));
                cs[q * 4 + 1] = f2bf((float)((w >> 8) & 255u));
                cs[q * 4 + 2] = f2bf((float)((w >> 16) & 255u));
                cs[q * 4 + 3] = f2bf((float)(w >> 24));
            }
            #pragma unroll
            for (int c = 0; c < CPT / 8; ++c) {
                short8 w8;
                #pragma unroll
                for (int j = 0; j < 8; ++j) w8[j] = (short)cs[c * 8 + j];
                *(short8*)&adjT[((kgA >> 3) + c) * BM * 8 + mA * 8] = w8;
            }
        }
        {
            float v[16];
            #pragma unroll
            for (int i = 0; i < 16; ++i)
                v[i] = xsrc[(size_t)(k0 + kgX + i) * F + nX];
            #pragma unroll
            for (int c = 0; c < 2; ++c) {
                short8 h1, h2, h3;
                #pragma unroll
                for (int j = 0; j < 8; ++j) {
                    float f = v[c * 8 + j];
                    unsigned short a1 = f2bf(f);
                    float r = f - bf2f(a1);
                    unsigned short a2 = f2bf(r);
                    float r2 = r - bf2f(a2);
                    h1[j] = (short)a1; h2[j] = (short)a2; h3[j] = (short)f2bf(r2);
                }
                int ko = (kgX >> 3) + c;
                *(short8*)&xs[0][ko * 1024 + nX * 8] = h1;
                *(short8*)&xs[1][ko * 1024 + nX * 8] = h2;
                *(short8*)&xs[2][ko * 1024 + nX * 8] = h3;
            }
        }
        __syncthreads();
        short8 afr[MT];
        #pragma unroll
        for (int mt = 0; mt < MT; ++mt)
            afr[mt] = *(const short8*)&adjT[(lane >> 4) * BM * 8 + (wv * RW + mt * 16 + (lane & 15)) * 8];
        #pragma unroll
        for (int s = 0; s < 3; ++s) {
            #pragma unroll
            for (int ct = 0; ct < 8; ++ct) {
                short8 bfr = *(const short8*)&xs[s][(lane >> 4) * 1024 + (ct * 16 + (lane & 15)) * 8];
                #pragma unroll
                for (int mt = 0; mt < MT; ++mt)
                    acc[mt][ct] = __builtin_amdgcn_mfma_f32_16x16x32_bf16(afr[mt], bfr, acc[mt][ct], 0, 0, 0);
            }
        }
    }

    float* Ag = Aout + (size_t)g * 32768;
    #pragma unroll
    for (int mt = 0; mt < MT; ++mt) {
        int r0 = mbase + wv * RW + mt * 16 + (lane >> 4) * 4;
        #pragma unroll
        for (int ct = 0; ct < 8; ++ct) {
            int col = ct * 16 + (lane & 15);
            #pragma unroll
            for (int r = 0; r < 4; ++r)
                Ag[(size_t)(r0 + r) * F + col] = acc[mt][ct][r];
        }
    }
}

// -------------------- conv GEMM on MFMA: h = relu([X | AGG] @ [Wr;Wl] + b) -----------
// 512 threads / 8 waves, wave tile 32 rows x 64 cols. LDS exactly 80 KB
// (Whi 64 KB copied from pre-split Wf + A-tile 16 KB) -> 2 blocks/CU, so the
// sibling block covers barrier stalls. W-lo streamed from L2 (1 of 3 passes).
// 3 MFMA passes (a1w1 + a2w1 + a1w2).
template<int NS, bool FIRST>
__global__ __launch_bounds__(512, 4) void k_gemm(const float* __restrict__ X,
                                                 float* __restrict__ A,
                                                 const float* __restrict__ AGG,
                                                 const unsigned short* __restrict__ Wf,
                                                 const float* __restrict__ bias) {
    constexpr int L2NS = (NS == 256) ? 8 : (NS == 128) ? 7 : 6;
    __shared__ uint4 Whi[32][128];     // 64 KB: [ko][col] short8 hi-frags
    __shared__ uint4 Afs[2][4][128];   // 16 KB: [split][ko][row^(ko<<2)] A-frags
    const int t = threadIdx.x;
    const int m0 = blockIdx.x * 128;
    const int lane = t & 63;
    const int wv = t >> 6, wr = wv >> 1, wc = wv & 1;
    const int l15 = lane & 15, lko = lane >> 4;
    const unsigned short* Wlo = Wf + 32768;

    // prologue: coalesced copy of pre-split W-hi fragments into LDS
    {
        const uint4* Wf4 = (const uint4*)Wf;
        uint4* Wd = (uint4*)Whi;
        #pragma unroll
        for (int i = 0; i < 8; ++i) Wd[t + i * 512] = Wf4[t + i * 512];
    }

    f32x4 acc[2][4];
    #pragma unroll
    for (int i = 0; i < 2; ++i)
        #pragma unroll
        for (int c = 0; c < 4; ++c) acc[i][c] = f32x4{0.f, 0.f, 0.f, 0.f};

    // staging: thread t stages row rs = t>>2, k-oct ck = t&3 (128B-coalesced per 4 lanes)
    const int rs = t >> 2, ck = t & 3;
    const int m_st = m0 + rs;
    const int g_st = m_st >> L2NS, n_st = m_st & (NS - 1);
    const float* xrow = FIRST ? (X + (size_t)m_st * F)
                              : (A + (size_t)g_st * 32768 + (size_t)(128 + n_st) * F);
    const float* arow = AGG + (size_t)g_st * 32768 + (size_t)n_st * F;

    for (int kt = 0; kt < 8; ++kt) {
        __syncthreads();  // prev-iter readers done (kt=0: fences Whi copy)
        {
            const float* srow = ((kt < 4) ? (xrow + kt * 32) : (arow + (kt - 4) * 32)) + ck * 8;
            float4 fa = *(const float4*)srow;
            float4 fb = *(const float4*)(srow + 4);
            float vv[8] = {fa.x, fa.y, fa.z, fa.w, fb.x, fb.y, fb.z, fb.w};
            short8 h1, h2;
            #pragma unroll
            for (int j = 0; j < 8; ++j) {
                unsigned short a1 = f2bf(vv[j]);
                unsigned short a2 = f2bf(vv[j] - bf2f(a1));
                h1[j] = (short)a1; h2[j] = (short)a2;
            }
            int rw = rs ^ (ck << 2);  // bank skew
            *reinterpret_cast<short8*>(&Afs[0][ck][rw]) = h1;
            *reinterpret_cast<short8*>(&Afs[1][ck][rw]) = h2;
        }
        __syncthreads();

        short8 a1f[2], a2f[2];
        #pragma unroll
        for (int mt = 0; mt < 2; ++mt) {
            int row = (wr * 32 + mt * 16 + l15) ^ (lko << 2);
            a1f[mt] = *reinterpret_cast<const short8*>(&Afs[0][lko][row]);
            a2f[mt] = *reinterpret_cast<const short8*>(&Afs[1][lko][row]);
        }
        const int kog = kt * 4 + lko;
        #pragma unroll
        for (int ct = 0; ct < 4; ++ct) {
            int col = wc * 64 + ct * 16 + l15;
            short8 w1 = *reinterpret_cast<const short8*>(&Whi[kog][col]);
            short8 w2 = *reinterpret_cast<const short8*>(Wlo + ((size_t)kog * 128 + col) * 8);
            #pragma unroll
            for (int mt = 0; mt < 2; ++mt) {
                acc[mt][ct] = __builtin_amdgcn_mfma_f32_16x16x32_bf16(a1f[mt], w1, acc[mt][ct], 0, 0, 0);
                acc[mt][ct] = __builtin_amdgcn_mfma_f32_16x16x32_bf16(a2f[mt], w1, acc[mt][ct], 0, 0, 0);
                acc[mt][ct] = __builtin_amdgcn_mfma_f32_16x16x32_bf16(a1f[mt], w2, acc[mt][ct], 0, 0, 0);
            }
        }
    }

    // epilogue: D col=lane&15 (per ct), row=(lane>>4)*4+reg
    #pragma unroll
    for (int ct = 0; ct < 4; ++ct) {
        int col = wc * 64 + ct * 16 + l15;
        float bv = bias[col];
        #pragma unroll
        for (int mt = 0; mt < 2; ++mt) {
            int r0 = m0 + wr * 32 + mt * 16 + lko * 4;
            #pragma unroll
            for (int r = 0; r < 4; ++r) {
                int m = r0 + r;
                int gg = m >> L2NS, nn = m & (NS - 1);
                A[(size_t)gg * 32768 + (size_t)nn * F + col] = fmaxf(acc[mt][ct][r] + bv, 0.f);
            }
        }
    }
}

// -------------------- top-k pool + readout + cmap update (1024 threads) --------------------
template<int N, int K, int STAGE>
__global__ __launch_bounds__(1024) void k_pool(float* __restrict__ A,
                                               float* __restrict__ R,
                                               int* __restrict__ cmap,
                                               const float* __restrict__ wp) {
    __shared__ float sc[N];
    __shared__ unsigned long long keys[N];
    __shared__ float hp[K * F];
    __shared__ int sel[K];
    __shared__ int inv[N];
    __shared__ float wn[F];
    __shared__ float gates[K];
    __shared__ float pmx[8 * F];
    __shared__ float psm[8 * F];
    __shared__ float snorm_s;
    const int g = blockIdx.x, t = threadIdx.x;
    const float* h = A + (size_t)g * 32768;
    const int lane = t & 63, wv16 = t >> 6;

    if (t < 64) {
        float v = wp[t] * wp[t] + wp[t + 64] * wp[t + 64];
        #pragma unroll
        for (int o = 32; o; o >>= 1) v += __shfl_xor(v, o);
        if (t == 0) snorm_s = sqrtf(v);
    }
    __syncthreads();
    if (t < 128) wn[t] = wp[t] / snorm_s;
    __syncthreads();

    {
        const int r16 = lane >> 4, l16 = lane & 15;
        float4 w0 = *(const float4*)&wn[l16 * 8];
        float4 w1 = *(const float4*)&wn[l16 * 8 + 4];
        #pragma unroll
        for (int n0 = 0; n0 < N; n0 += 64) {
            int r = n0 + wv16 * 4 + r16;
            const float* hr = h + (size_t)r * F + l16 * 8;
            float4 v0 = *(const float4*)hr;
            float4 v1 = *(const float4*)(hr + 4);
            float p = v0.x * w0.x + v0.y * w0.y + v0.z * w0.z + v0.w * w0.w
                    + v1.x * w1.x + v1.y * w1.y + v1.z * w1.z + v1.w * w1.w;
            p += __shfl_xor(p, 1); p += __shfl_xor(p, 2);
            p += __shfl_xor(p, 4); p += __shfl_xor(p, 8);
            if (l16 == 0) sc[r] = p;
        }
    }
    __syncthreads();

    if (t < N) {
        unsigned u = __float_as_uint(sc[t]);
        u = (u & 0x80000000u) ? ~u : (u | 0x80000000u);
        keys[t] = ((unsigned long long)u << 32) | (unsigned)(~t);
    }
    __syncthreads();
    for (int kk = 2; kk <= N; kk <<= 1) {
        for (int j = kk >> 1; j > 0; j >>= 1) {
            if (t < N) {
                int ixj = t ^ j;
                if (ixj > t) {
                    unsigned long long a = keys[t], b = keys[ixj];
                    bool up = (t & kk) == 0;
                    if (up ? (a < b) : (a > b)) { keys[t] = b; keys[ixj] = a; }
                }
            }
            __syncthreads();
        }
    }

    if (t < K) sel[t] = (int)(~(unsigned)keys[t]);
    if (t < N) inv[t] = -1;
    __syncthreads();
    if (t < K) {
        inv[sel[t]] = t;
        gates[t] = tanhf(sc[sel[t]]);
    }
    __syncthreads();
    if (t < 256) {
        int c = (STAGE == 1) ? t : cmap[g * 256 + t];
        cmap[g * 256 + t] = (c >= 0) ? inv[c] : -1;
    }

    {
        const int f = t & 127, seg = t >> 7;
        float mx = -INFINITY, sm = 0.f;
        for (int j = seg; j < K; j += 8) {
            float v = h[(size_t)sel[j] * F + f] * gates[j];
            hp[j * F + f] = v;
            mx = fmaxf(mx, v);
            sm += v;
        }
        pmx[seg * F + f] = mx;
        psm[seg * F + f] = sm;
    }
    __syncthreads();

    if (t < 128) {
        float m = -INFINITY, s = 0.f;
        #pragma unroll
        for (int q = 0; q < 8; ++q) {
            m = fmaxf(m, pmx[q * F + t]);
            s += psm[q * F + t];
        }
        R[(size_t)g * 768 + (STAGE - 1) * 256 + t] = m;
        R[(size_t)g * 768 + (STAGE - 1) * 256 + 128 + t] = s * (1.0f / K);
    }

    if (STAGE < 3) {
        float4* dst = (float4*)(A + (size_t)g * 32768 + 128 * F);
        const float4* srcp = (const float4*)hp;
        for (int i = t; i < K * F / 4; i += 1024) dst[i] = srcp[i];
    }
}

// -------------------- final MLP + log_softmax (split-K, 1024 threads) --------------------
__global__ __launch_bounds__(1024) void k_mlp(const float* __restrict__ R,
                                              const float* __restrict__ W1, const float* __restrict__ b1,
                                              const float* __restrict__ W2, const float* __restrict__ b2,
                                              const float* __restrict__ W3, const float* __restrict__ b3,
                                              float* __restrict__ out) {
    __shared__ float z[768];
    __shared__ float part[8][128];
    __shared__ float z2[128];
    __shared__ float z3[64];
    __shared__ float lg[10];
    __shared__ float lse;
    const int g = blockIdx.x, t = threadIdx.x;

    if (t < 768) z[t] = R[(size_t)g * 768 + t];
    __syncthreads();

    {
        const int f = t & 127, seg = t >> 7;
        float acc = 0.f;
        const float* w = W1 + (size_t)(seg * 96) * 128 + f;
        const float* zz = z + seg * 96;
        #pragma unroll 8
        for (int k = 0; k < 96; ++k) acc = fmaf(zz[k], w[(size_t)k * 128], acc);
        part[seg][f] = acc;
    }
    __syncthreads();
    if (t < 128) {
        float a = b1[t];
        #pragma unroll
        for (int q = 0; q < 8; ++q) a += part[q][t];
        z2[t] = fmaxf(a, 0.f);
    }
    __syncthreads();

    if (t < 512) {
        const int f = t & 63, seg = t >> 6;
        float acc = 0.f;
        const float* w = W2 + (size_t)(seg * 16) * 64 + f;
        const float* zz = z2 + seg * 16;
        #pragma unroll
        for (int k = 0; k < 16; ++k) acc = fmaf(zz[k], w[(size_t)k * 64], acc);
        part[seg][f] = acc;
    }
    __syncthreads();
    if (t < 64) {
        float a = b2[t];
        #pragma unroll
        for (int q = 0; q < 8; ++q) a += part[q][t];
        z3[t] = fmaxf(a, 0.f);
    }
    __syncthreads();

    if (t < 10) {
        float a3 = b3[t];
        #pragma unroll 8
        for (int k = 0; k < 64; ++k) a3 = fmaf(z3[k], W3[(size_t)k * 10 + t], a3);
        lg[t] = a3;
    }
    __syncthreads();

    if (t == 0) {
        float m = lg[0];
        for (int c = 1; c < 10; ++c) m = fmaxf(m, lg[c]);
        float s = 0.f;
        for (int c = 0; c < 10; ++c) s += expf(lg[c] - m);
        lse = m + logf(s);
    }
    __syncthreads();
    if (t < 10) out[(size_t)g * 10 + t] = lg[t] - lse;
}

extern "C" void kernel_launch(void* const* d_in, const int* in_sizes, int n_in,
                              void* d_out, int out_size, void* d_ws, size_t ws_size,
                              hipStream_t stream) {
    (void)in_sizes; (void)n_in; (void)out_size; (void)ws_size;
    const float* x    = (const float*)d_in[0];
    const int*   src  = (const int*)d_in[1];
    const int*   dst  = (const int*)d_in[2];
    const float* Wr1  = (const float*)d_in[3];
    const float* Wrel1= (const float*)d_in[4];
    const float* b1   = (const float*)d_in[5];
    const float* wp1  = (const float*)d_in[6];
    const float* Wr2  = (const float*)d_in[7];
    const float* Wrel2= (const float*)d_in[8];
    const float* b2   = (const float*)d_in[9];
    const float* wp2  = (const float*)d_in[10];
    const float* Wr3  = (const float*)d_in[11];
    const float* Wrel3= (const float*)d_in[12];
    const float* b3   = (const float*)d_in[13];
    const float* wp3  = (const float*)d_in[14];
    const float* L1w  = (const float*)d_in[15];
    const float* L1b  = (const float*)d_in[16];
    const float* L2w  = (const float*)d_in[17];
    const float* L2b  = (const float*)d_in[18];
    const float* L3w  = (const float*)d_in[19];
    const float* L3b  = (const float*)d_in[20];

    float* A    = (float*)d_ws;                        // G*32768 f32  (h + pooled rows)
    int*   cmap = (int*)(A + (size_t)G * 32768);       // G*256 i32
    float* R    = (float*)(cmap + (size_t)G * 256);    // G*768 f32
    float* AGG  = R + (size_t)G * 768;                 // G*32768 f32  (agg output)
    unsigned short* Wf = (unsigned short*)(AGG + (size_t)G * 32768);  // 3*65536 shorts
    float* out  = (float*)d_out;

    // W pre-split (once per launch, all 3 stages)
    k_wsplit<<<384, 256, 0, stream>>>(Wr1, Wrel1, Wr2, Wrel2, Wr3, Wrel3, Wf);

    // stage 1
    k_agg<256, 128, false><<<G * 2, 256, 0, stream>>>(x, src, dst, nullptr, A, AGG);
    k_gemm<256, true><<<512, 512, 0, stream>>>(x, A, AGG, Wf, b1);
    k_pool<256, 128, 1><<<G, 1024, 0, stream>>>(A, R, cmap, wp1);
    // stage 2
    k_agg<128, 128, true><<<G, 256, 0, stream>>>(x, src, dst, cmap, A, AGG);
    k_gemm<128, false><<<256, 512, 0, stream>>>(nullptr, A, AGG, Wf + 65536, b2);
    k_pool<128, 64, 2><<<G, 1024, 0, stream>>>(A, R, cmap, wp2);
    // stage 3
    k_agg<64, 64, true><<<G, 256, 0, stream>>>(x, src, dst, cmap, A, AGG);
    k_gemm<64, false><<<128, 512, 0, stream>>>(nullptr, A, AGG, Wf + 131072, b3);
    k_pool<64, 32, 3><<<G, 1024, 0, stream>>>(A, R, cmap, wp3);
    // head
    k_mlp<<<G, 1024, 0, stream>>>(R, L1w, L1b, L2w, L2b, L3w, L3b, out);
}